// Round 2
// baseline (3324.391 us; speedup 1.0000x reference)
//
#include <hip/hip_runtime.h>

#define N_NODES 100000
#define E_EDGES 300000
#define N_GRAPHS 2048

typedef float  floatx4 __attribute__((ext_vector_type(4)));
typedef short  shortx8 __attribute__((ext_vector_type(8)));

__device__ __forceinline__ float bf2f(unsigned short u) {
  return __uint_as_float(((unsigned int)u) << 16);
}
__device__ __forceinline__ unsigned short f2bf(float f) {
  unsigned int u = __float_as_uint(f);
  u += 0x7FFFu + ((u >> 16) & 1u);
  return (unsigned short)(u >> 16);
}

// packed bf16 atomic add (gfx950 global_atomic_pk_add_bf16) for low-mem fallback
__device__ __forceinline__ void atomic_pk_add_bf16(unsigned int* p, unsigned int v) {
  asm volatile("global_atomic_pk_add_bf16 %0, %1, off" : : "v"(p), "v"(v) : "memory");
}

// ---------------- embed: H[n,128] = bf16(X[n,40] @ We[40,128] + be) ----------
__global__ __launch_bounds__(128)
void embed_kernel(const float* __restrict__ X, const float* __restrict__ W,
                  const float* __restrict__ b, unsigned short* __restrict__ H) {
  __shared__ float Ws[40 * 128];
  __shared__ float Xs[16 * 40];
  const int t = threadIdx.x;
  const int nb = blockIdx.x * 16;
  for (int i = t; i < 40 * 128; i += 128) Ws[i] = W[i];
  for (int i = t; i < 16 * 40; i += 128) Xs[i] = X[(size_t)nb * 40 + i];
  __syncthreads();
  const float bias = b[t];
  for (int n = 0; n < 16; n++) {
    float acc = bias;
#pragma unroll
    for (int k = 0; k < 40; k++) acc = fmaf(Xs[n * 40 + k], Ws[k * 128 + t], acc);
    H[(size_t)(nb + n) * 128 + t] = f2bf(acc);
  }
}

// ---------------- Z = (1+eps[l]) * H : fp32 variant --------------------------
__global__ __launch_bounds__(256)
void init_z_f32_kernel(const unsigned short* __restrict__ H, float* __restrict__ Z,
                       const float* __restrict__ eps, int l) {
  const float sc = 1.0f + eps[l];
  const size_t i4 = ((size_t)blockIdx.x * 256 + threadIdx.x) * 4;
  uint2 hv = *(const uint2*)(H + i4);
  float4 z;
  z.x = sc * bf2f((unsigned short)(hv.x & 0xFFFF));
  z.y = sc * bf2f((unsigned short)(hv.x >> 16));
  z.z = sc * bf2f((unsigned short)(hv.y & 0xFFFF));
  z.w = sc * bf2f((unsigned short)(hv.y >> 16));
  *(float4*)(Z + i4) = z;
}

// ---------------- Z = (1+eps[l]) * H : bf16 variant (low-mem) ----------------
__global__ __launch_bounds__(256)
void init_z_bf16_kernel(const unsigned short* __restrict__ H, unsigned short* __restrict__ Z,
                        const float* __restrict__ eps, int l) {
  const float sc = 1.0f + eps[l];
  const size_t i4 = ((size_t)blockIdx.x * 256 + threadIdx.x) * 4;
  uint2 hv = *(const uint2*)(H + i4);
  unsigned short z[4];
  z[0] = f2bf(sc * bf2f((unsigned short)(hv.x & 0xFFFF)));
  z[1] = f2bf(sc * bf2f((unsigned short)(hv.x >> 16)));
  z[2] = f2bf(sc * bf2f((unsigned short)(hv.y & 0xFFFF)));
  z[3] = f2bf(sc * bf2f((unsigned short)(hv.y >> 16)));
  *(uint2*)(Z + i4) = *(uint2*)z;
}

// ---------------- Z[dst] += H[src] : fp32 atomics ----------------------------
__global__ __launch_bounds__(256)
void scatter_f32_kernel(const unsigned short* __restrict__ H, float* __restrict__ Z,
                        const int* __restrict__ ei, int cshift, int D) {
  const int tid = blockIdx.x * 256 + threadIdx.x;
  const int e = tid >> cshift;
  const int c = (tid & ((1 << cshift) - 1)) * 4;
  const int s = ei[e];
  const int d = ei[E_EDGES + e];
  uint2 hv = *(const uint2*)(H + (size_t)s * D + c);
  float* zp = Z + (size_t)d * D + c;
  unsafeAtomicAdd(zp + 0, bf2f((unsigned short)(hv.x & 0xFFFF)));
  unsafeAtomicAdd(zp + 1, bf2f((unsigned short)(hv.x >> 16)));
  unsafeAtomicAdd(zp + 2, bf2f((unsigned short)(hv.y & 0xFFFF)));
  unsafeAtomicAdd(zp + 3, bf2f((unsigned short)(hv.y >> 16)));
}

// ---------------- Z[dst] += H[src] : packed bf16 atomics (low-mem) -----------
__global__ __launch_bounds__(256)
void scatter_bf16_kernel(const unsigned short* __restrict__ H, unsigned short* __restrict__ Z,
                         const int* __restrict__ ei, int cshift, int D) {
  const int tid = blockIdx.x * 256 + threadIdx.x;
  const int e = tid >> cshift;
  const int c = (tid & ((1 << cshift) - 1)) * 4;
  const int s = ei[e];
  const int d = ei[E_EDGES + e];
  uint2 hv = *(const uint2*)(H + (size_t)s * D + c);
  unsigned int* zp = (unsigned int*)(Z + (size_t)d * D + c);
  atomic_pk_add_bf16(zp + 0, hv.x);
  atomic_pk_add_bf16(zp + 1, hv.y);
}

// ---------------- C[M,N] = act(A[M,K] @ W[K,N] + bias), bf16 MFMA ------------
// A: fp32 or bf16 (template). W fp32, C bf16. 128x128 tile, BK=32, 4 waves 2x2.
template <bool ABF16, bool RELU>
__global__ __launch_bounds__(256)
void gemm_kernel(const void* __restrict__ A_, const float* __restrict__ W,
                 const float* __restrict__ bias, unsigned short* __restrict__ C,
                 int M, int K, int N) {
  constexpr int BM = 128, BN = 128, BK = 32, LDT = 40;  // LDT: padded stride (bf16 elems)
  __shared__ unsigned short As[BM * LDT];
  __shared__ unsigned short Bs[BN * LDT];
  const int tid = threadIdx.x;
  const int lane = tid & 63;
  const int wave = tid >> 6;
  const int m0 = blockIdx.x * BM;
  const int n0 = blockIdx.y * BN;
  const int wm = (wave & 1) * 64;
  const int wn = (wave >> 1) * 64;

  floatx4 acc[4][4];
#pragma unroll
  for (int i = 0; i < 4; i++)
#pragma unroll
    for (int j = 0; j < 4; j++) acc[i][j] = (floatx4){0.f, 0.f, 0.f, 0.f};

  const int a_c4 = (tid & 7) * 4;   // elem col within tile
  const int a_rb = tid >> 3;        // 0..31
  const int b_n  = tid & 127;
  const int b_kh = (tid >> 7) * 16;

  for (int k0 = 0; k0 < K; k0 += BK) {
    // stage A tile (128 x 32) -> As[row*LDT + col], bf16
#pragma unroll
    for (int i = 0; i < 4; i++) {
      int row = a_rb + 32 * i;
      int grow = m0 + row;
      if (grow >= M) grow = M - 1;
      unsigned short v[4];
      if (ABF16) {
        *(uint2*)v = *(const uint2*)((const unsigned short*)A_ + (size_t)grow * K + k0 + a_c4);
      } else {
        float4 f = *(const float4*)((const float*)A_ + (size_t)grow * K + k0 + a_c4);
        v[0] = f2bf(f.x); v[1] = f2bf(f.y); v[2] = f2bf(f.z); v[3] = f2bf(f.w);
      }
      *(uint2*)&As[row * LDT + a_c4] = *(uint2*)v;
    }
    // stage B tile transposed: Bs[n*LDT + k] = bf16(W[k0+k][n0+n]), 16 k per thread
    {
      unsigned short v[16];
#pragma unroll
      for (int j = 0; j < 16; j++)
        v[j] = f2bf(W[(size_t)(k0 + b_kh + j) * N + n0 + b_n]);
      *(uint4*)&Bs[b_n * LDT + b_kh]     = *(uint4*)&v[0];
      *(uint4*)&Bs[b_n * LDT + b_kh + 8] = *(uint4*)&v[8];
    }
    __syncthreads();

    const int fr = lane & 15;
    const int fk = (lane >> 4) * 8;
    shortx8 af[4], bf[4];
#pragma unroll
    for (int i = 0; i < 4; i++)
      af[i] = *(const shortx8*)&As[(wm + i * 16 + fr) * LDT + fk];
#pragma unroll
    for (int j = 0; j < 4; j++)
      bf[j] = *(const shortx8*)&Bs[(wn + j * 16 + fr) * LDT + fk];
#pragma unroll
    for (int i = 0; i < 4; i++)
#pragma unroll
      for (int j = 0; j < 4; j++)
        acc[i][j] = __builtin_amdgcn_mfma_f32_16x16x32_bf16(af[i], bf[j], acc[i][j], 0, 0, 0);
    __syncthreads();
  }

  // epilogue: C/D layout col=lane&15, row=(lane>>4)*4+r  [m89/m91-verified]
  const int fr = lane & 15;
  const int q = lane >> 4;
#pragma unroll
  for (int j = 0; j < 4; j++) {
    int col = n0 + wn + j * 16 + fr;
    float bj = bias[col];
#pragma unroll
    for (int i = 0; i < 4; i++) {
#pragma unroll
      for (int r = 0; r < 4; r++) {
        int row = m0 + wm + i * 16 + q * 4 + r;
        if (row < M) {
          float v = acc[i][j][r] + bj;
          if (RELU) v = fmaxf(v, 0.f);
          C[(size_t)row * N + col] = f2bf(v);
        }
      }
    }
  }
}

// ---------------- readout: out[g] = b + sum_{i in g} dot(H[i,:512], w) -------
__global__ __launch_bounds__(256)
void init_out_kernel(float* __restrict__ out, const float* __restrict__ b_task) {
  int g = blockIdx.x * 256 + threadIdx.x;
  if (g < N_GRAPHS) out[g] = b_task[0];
}

__global__ __launch_bounds__(256)
void dot_pool_kernel(const unsigned short* __restrict__ H, const float* __restrict__ w,
                     const int* __restrict__ batch, float* __restrict__ out) {
  const int node = blockIdx.x * 4 + (threadIdx.x >> 6);
  const int lane = threadIdx.x & 63;
  uint4 hv = *(const uint4*)(H + (size_t)node * 512 + lane * 8);
  float4 w0 = *(const float4*)(w + lane * 8);
  float4 w1 = *(const float4*)(w + lane * 8 + 4);
  unsigned int p[4] = {hv.x, hv.y, hv.z, hv.w};
  float v = 0.f;
  v = fmaf(bf2f((unsigned short)(p[0] & 0xFFFF)), w0.x, v);
  v = fmaf(bf2f((unsigned short)(p[0] >> 16)),    w0.y, v);
  v = fmaf(bf2f((unsigned short)(p[1] & 0xFFFF)), w0.z, v);
  v = fmaf(bf2f((unsigned short)(p[1] >> 16)),    w0.w, v);
  v = fmaf(bf2f((unsigned short)(p[2] & 0xFFFF)), w1.x, v);
  v = fmaf(bf2f((unsigned short)(p[2] >> 16)),    w1.y, v);
  v = fmaf(bf2f((unsigned short)(p[3] & 0xFFFF)), w1.z, v);
  v = fmaf(bf2f((unsigned short)(p[3] >> 16)),    w1.w, v);
#pragma unroll
  for (int off = 32; off > 0; off >>= 1) v += __shfl_down(v, off);
  if (lane == 0) unsafeAtomicAdd(&out[batch[node]], v);
}

extern "C" void kernel_launch(void* const* d_in, const int* in_sizes, int n_in,
                              void* d_out, int out_size, void* d_ws, size_t ws_size,
                              hipStream_t stream) {
  const float* x       = (const float*)d_in[0];
  const int*   ei      = (const int*)d_in[1];
  const int*   batch   = (const int*)d_in[2];
  const float* W_embed = (const float*)d_in[3];
  const float* b_embed = (const float*)d_in[4];
  const float* eps     = (const float*)d_in[5];
  const float* W1[3] = {(const float*)d_in[6],  (const float*)d_in[10], (const float*)d_in[14]};
  const float* B1[3] = {(const float*)d_in[7],  (const float*)d_in[11], (const float*)d_in[15]};
  const float* W2[3] = {(const float*)d_in[8],  (const float*)d_in[12], (const float*)d_in[16]};
  const float* B2[3] = {(const float*)d_in[9],  (const float*)d_in[13], (const float*)d_in[17]};
  const float* W_task = (const float*)d_in[18];
  const float* b_task = (const float*)d_in[19];
  float* out = (float*)d_out;

  const int Din[3]  = {128, 256, 256};
  const int Dhid[3] = {256, 256, 512};
  const int Dout[3] = {256, 256, 512};

  const size_t SZ_H  = (size_t)N_NODES * 256 * 2;  // 51.2 MB (H, widths <= 256)
  const size_t SZ_T  = (size_t)N_NODES * 512 * 2;  // 102.4 MB (T, max 512 wide)
  const size_t SZ_Zf = (size_t)N_NODES * 256 * 4;  // 102.4 MB (Z fp32)
  const size_t SZ_Zb = (size_t)N_NODES * 256 * 2;  // 51.2 MB (Z bf16, low-mem)

  const bool big = ws_size >= SZ_H + SZ_T + SZ_Zf;  // 256.0 MB layout

  // big layout:   [RH 51.2 | RT 102.4 | RZ(fp32) 102.4]; H3(512,bf16) -> RZ
  // small layout: [RH 51.2 | RZb 51.2 | RT 102.4];       H3(512,bf16) -> RH+RZb
  unsigned short* RH = (unsigned short*)d_ws;
  unsigned short* RT;
  float*          RZf = nullptr;
  unsigned short* RZb = nullptr;
  unsigned short* H3;
  if (big) {
    RT  = (unsigned short*)((char*)d_ws + SZ_H);
    RZf = (float*)((char*)d_ws + SZ_H + SZ_T);
    H3  = (unsigned short*)RZf;
  } else {
    RZb = (unsigned short*)((char*)d_ws + SZ_H);
    RT  = (unsigned short*)((char*)d_ws + SZ_H + SZ_Zb);
    H3  = RH;  // spans RH+RZb (both dead by then)
  }

  // embed -> H0 (128 wide) in RH
  embed_kernel<<<N_NODES / 16, 128, 0, stream>>>(x, W_embed, b_embed, RH);

  for (int l = 0; l < 3; l++) {
    const int di = Din[l];
    const int cshift = (di == 128) ? 5 : 6;
    const int nz_blocks = (N_NODES * di) / (256 * 4);
    const int sc_blocks = (E_EDGES * (di / 4)) / 256;
    dim3 g1((N_NODES + 127) / 128, Dhid[l] / 128);
    dim3 g2((N_NODES + 127) / 128, Dout[l] / 128);
    unsigned short* Hdst = (l == 2) ? H3 : RH;

    if (big) {
      init_z_f32_kernel<<<nz_blocks, 256, 0, stream>>>(RH, RZf, eps, l);
      scatter_f32_kernel<<<sc_blocks, 256, 0, stream>>>(RH, RZf, ei, cshift, di);
      gemm_kernel<false, true><<<g1, 256, 0, stream>>>(RZf, W1[l], B1[l], RT, N_NODES, di, Dhid[l]);
    } else {
      init_z_bf16_kernel<<<nz_blocks, 256, 0, stream>>>(RH, RZb, eps, l);
      scatter_bf16_kernel<<<sc_blocks, 256, 0, stream>>>(RH, RZb, ei, cshift, di);
      gemm_kernel<true, true><<<g1, 256, 0, stream>>>(RZb, W1[l], B1[l], RT, N_NODES, di, Dhid[l]);
    }
    if (l < 2)
      gemm_kernel<true, true><<<g2, 256, 0, stream>>>(RT, W2[l], B2[l], Hdst, N_NODES, Dhid[l], Dout[l]);
    else
      gemm_kernel<true, false><<<g2, 256, 0, stream>>>(RT, W2[l], B2[l], Hdst, N_NODES, Dhid[l], Dout[l]);
  }

  // readout (pool and task head fused: out[g] = b + sum dot(h_i, w))
  init_out_kernel<<<(N_GRAPHS + 255) / 256, 256, 0, stream>>>(out, b_task);
  dot_pool_kernel<<<N_NODES / 4, 256, 0, stream>>>(H3, W_task, batch, out);
}

// Round 3
// 941.588 us; speedup vs baseline: 3.5306x; 3.5306x over previous
//
#include <hip/hip_runtime.h>

#define N_NODES 100000
#define E_EDGES 300000
#define N_GRAPHS 2048

typedef float  floatx4 __attribute__((ext_vector_type(4)));
typedef short  shortx8 __attribute__((ext_vector_type(8)));

__device__ __forceinline__ float bf2f(unsigned short u) {
  return __uint_as_float(((unsigned int)u) << 16);
}
__device__ __forceinline__ unsigned short f2bf(float f) {
  unsigned int u = __float_as_uint(f);
  u += 0x7FFFu + ((u >> 16) & 1u);
  return (unsigned short)(u >> 16);
}

// ---------------- embed: H[n,128] = bf16(X[n,40] @ We[40,128] + be) ----------
__global__ __launch_bounds__(128)
void embed_kernel(const float* __restrict__ X, const float* __restrict__ W,
                  const float* __restrict__ b, unsigned short* __restrict__ H) {
  __shared__ float Ws[40 * 128];
  __shared__ float Xs[16 * 40];
  const int t = threadIdx.x;
  const int nb = blockIdx.x * 16;
  for (int i = t; i < 40 * 128; i += 128) Ws[i] = W[i];
  for (int i = t; i < 16 * 40; i += 128) Xs[i] = X[(size_t)nb * 40 + i];
  __syncthreads();
  const float bias = b[t];
  for (int n = 0; n < 16; n++) {
    float acc = bias;
#pragma unroll
    for (int k = 0; k < 40; k++) acc = fmaf(Xs[n * 40 + k], Ws[k * 128 + t], acc);
    H[(size_t)(nb + n) * 128 + t] = f2bf(acc);
  }
}

// ---------------- CSR build: zero, histogram, scan, fill ---------------------
__global__ __launch_bounds__(256)
void zero_kernel(int* __restrict__ p, int n) {
  int i = blockIdx.x * 256 + threadIdx.x;
  if (i < n) p[i] = 0;
}

__global__ __launch_bounds__(256)
void hist_kernel(const int* __restrict__ ei, int* __restrict__ deg) {
  int e = blockIdx.x * 256 + threadIdx.x;
  if (e < E_EDGES) atomicAdd(&deg[ei[E_EDGES + e]], 1);
}

// block-local exclusive scan (1024 elems/block, 256 thr x 4); blk_sums optional
__global__ __launch_bounds__(256)
void scan_blk_kernel(const int* __restrict__ in, int* __restrict__ out,
                     int* __restrict__ blk_sums, int n_in, int n_out) {
  __shared__ int sm[256];
  const int t = threadIdx.x;
  const int base = blockIdx.x * 1024 + t * 4;
  int d0 = (base + 0 < n_in) ? in[base + 0] : 0;
  int d1 = (base + 1 < n_in) ? in[base + 1] : 0;
  int d2 = (base + 2 < n_in) ? in[base + 2] : 0;
  int d3 = (base + 3 < n_in) ? in[base + 3] : 0;
  int s = d0 + d1 + d2 + d3;
  sm[t] = s;
  __syncthreads();
  for (int off = 1; off < 256; off <<= 1) {
    int v = (t >= off) ? sm[t - off] : 0;
    __syncthreads();
    sm[t] += v;
    __syncthreads();
  }
  int excl = sm[t] - s;
  if (base + 0 < n_out) out[base + 0] = excl;
  if (base + 1 < n_out) out[base + 1] = excl + d0;
  if (base + 2 < n_out) out[base + 2] = excl + d0 + d1;
  if (base + 3 < n_out) out[base + 3] = excl + d0 + d1 + d2;
  if (t == 255 && blk_sums) blk_sums[blockIdx.x] = sm[255];
}

// add per-block offsets; produce final row_ptr and cursor copy
__global__ __launch_bounds__(256)
void scan_fix_kernel(int* __restrict__ row_ptr, const int* __restrict__ blk_off,
                     int* __restrict__ cursor) {
  int i = blockIdx.x * 256 + threadIdx.x;
  if (i <= N_NODES) {
    int v = row_ptr[i] + blk_off[i >> 10];
    row_ptr[i] = v;
    if (i < N_NODES) cursor[i] = v;
  }
}

__global__ __launch_bounds__(256)
void fill_kernel(const int* __restrict__ ei, int* __restrict__ cursor,
                 int* __restrict__ csr_src) {
  int e = blockIdx.x * 256 + threadIdx.x;
  if (e < E_EDGES) {
    int d = ei[E_EDGES + e];
    int slot = atomicAdd(&cursor[d], 1);
    csr_src[slot] = ei[e];
  }
}

// ---------------- gather: Z[d] = (1+eps)*H[d] + sum_{s->d} H[s]  (fp32) ------
// one wave per dst node; NV bf16 feats per lane (D = NV*64)
template <int NV>
__global__ __launch_bounds__(256)
void gather_kernel(const unsigned short* __restrict__ H, float* __restrict__ Z,
                   const int* __restrict__ row_ptr, const int* __restrict__ csr,
                   const float* __restrict__ eps, int l) {
  const int D = NV * 64;
  const int node = blockIdx.x * 4 + (threadIdx.x >> 6);
  const int lane = threadIdx.x & 63;
  const float sc = 1.0f + eps[l];
  const unsigned short* hp0 = H + (size_t)node * D + lane * NV;
  float acc[NV];
  if constexpr (NV == 4) {
    uint2 hv = *(const uint2*)hp0;
    acc[0] = sc * bf2f((unsigned short)(hv.x & 0xFFFF));
    acc[1] = sc * bf2f((unsigned short)(hv.x >> 16));
    acc[2] = sc * bf2f((unsigned short)(hv.y & 0xFFFF));
    acc[3] = sc * bf2f((unsigned short)(hv.y >> 16));
  } else {
    unsigned int hv = *(const unsigned int*)hp0;
    acc[0] = sc * bf2f((unsigned short)(hv & 0xFFFF));
    acc[1] = sc * bf2f((unsigned short)(hv >> 16));
  }
  const int e0 = row_ptr[node];
  const int e1 = row_ptr[node + 1];
  int e = e0;
  for (; e + 2 <= e1; e += 2) {
    int s0 = csr[e], s1 = csr[e + 1];
    const unsigned short* p0 = H + (size_t)s0 * D + lane * NV;
    const unsigned short* p1 = H + (size_t)s1 * D + lane * NV;
    if constexpr (NV == 4) {
      uint2 a = *(const uint2*)p0;
      uint2 b = *(const uint2*)p1;
      acc[0] += bf2f((unsigned short)(a.x & 0xFFFF)) + bf2f((unsigned short)(b.x & 0xFFFF));
      acc[1] += bf2f((unsigned short)(a.x >> 16))    + bf2f((unsigned short)(b.x >> 16));
      acc[2] += bf2f((unsigned short)(a.y & 0xFFFF)) + bf2f((unsigned short)(b.y & 0xFFFF));
      acc[3] += bf2f((unsigned short)(a.y >> 16))    + bf2f((unsigned short)(b.y >> 16));
    } else {
      unsigned int a = *(const unsigned int*)p0;
      unsigned int b = *(const unsigned int*)p1;
      acc[0] += bf2f((unsigned short)(a & 0xFFFF)) + bf2f((unsigned short)(b & 0xFFFF));
      acc[1] += bf2f((unsigned short)(a >> 16))    + bf2f((unsigned short)(b >> 16));
    }
  }
  if (e < e1) {
    int s0 = csr[e];
    const unsigned short* p0 = H + (size_t)s0 * D + lane * NV;
    if constexpr (NV == 4) {
      uint2 a = *(const uint2*)p0;
      acc[0] += bf2f((unsigned short)(a.x & 0xFFFF));
      acc[1] += bf2f((unsigned short)(a.x >> 16));
      acc[2] += bf2f((unsigned short)(a.y & 0xFFFF));
      acc[3] += bf2f((unsigned short)(a.y >> 16));
    } else {
      unsigned int a = *(const unsigned int*)p0;
      acc[0] += bf2f((unsigned short)(a & 0xFFFF));
      acc[1] += bf2f((unsigned short)(a >> 16));
    }
  }
  float* zp = Z + (size_t)node * D + lane * NV;
  if constexpr (NV == 4) {
    *(float4*)zp = (float4){acc[0], acc[1], acc[2], acc[3]};
  } else {
    *(float2*)zp = (float2){acc[0], acc[1]};
  }
}

// ---------------- C[M,N] = act(A[M,K] @ W[K,N] + bias), bf16 MFMA ------------
template <bool ABF16, bool RELU>
__global__ __launch_bounds__(256)
void gemm_kernel(const void* __restrict__ A_, const float* __restrict__ W,
                 const float* __restrict__ bias, unsigned short* __restrict__ C,
                 int M, int K, int N) {
  constexpr int BM = 128, BN = 128, BK = 32, LDT = 40;
  __shared__ unsigned short As[BM * LDT];
  __shared__ unsigned short Bs[BN * LDT];
  const int tid = threadIdx.x;
  const int lane = tid & 63;
  const int wave = tid >> 6;
  const int m0 = blockIdx.x * BM;
  const int n0 = blockIdx.y * BN;
  const int wm = (wave & 1) * 64;
  const int wn = (wave >> 1) * 64;

  floatx4 acc[4][4];
#pragma unroll
  for (int i = 0; i < 4; i++)
#pragma unroll
    for (int j = 0; j < 4; j++) acc[i][j] = (floatx4){0.f, 0.f, 0.f, 0.f};

  const int a_c4 = (tid & 7) * 4;
  const int a_rb = tid >> 3;
  const int b_n  = tid & 127;
  const int b_kh = (tid >> 7) * 16;

  for (int k0 = 0; k0 < K; k0 += BK) {
#pragma unroll
    for (int i = 0; i < 4; i++) {
      int row = a_rb + 32 * i;
      int grow = m0 + row;
      if (grow >= M) grow = M - 1;
      unsigned short v[4];
      if (ABF16) {
        *(uint2*)v = *(const uint2*)((const unsigned short*)A_ + (size_t)grow * K + k0 + a_c4);
      } else {
        float4 f = *(const float4*)((const float*)A_ + (size_t)grow * K + k0 + a_c4);
        v[0] = f2bf(f.x); v[1] = f2bf(f.y); v[2] = f2bf(f.z); v[3] = f2bf(f.w);
      }
      *(uint2*)&As[row * LDT + a_c4] = *(uint2*)v;
    }
    {
      unsigned short v[16];
#pragma unroll
      for (int j = 0; j < 16; j++)
        v[j] = f2bf(W[(size_t)(k0 + b_kh + j) * N + n0 + b_n]);
      *(uint4*)&Bs[b_n * LDT + b_kh]     = *(uint4*)&v[0];
      *(uint4*)&Bs[b_n * LDT + b_kh + 8] = *(uint4*)&v[8];
    }
    __syncthreads();

    const int fr = lane & 15;
    const int fk = (lane >> 4) * 8;
    shortx8 af[4], bf[4];
#pragma unroll
    for (int i = 0; i < 4; i++)
      af[i] = *(const shortx8*)&As[(wm + i * 16 + fr) * LDT + fk];
#pragma unroll
    for (int j = 0; j < 4; j++)
      bf[j] = *(const shortx8*)&Bs[(wn + j * 16 + fr) * LDT + fk];
#pragma unroll
    for (int i = 0; i < 4; i++)
#pragma unroll
      for (int j = 0; j < 4; j++)
        acc[i][j] = __builtin_amdgcn_mfma_f32_16x16x32_bf16(af[i], bf[j], acc[i][j], 0, 0, 0);
    __syncthreads();
  }

  const int fr = lane & 15;
  const int q = lane >> 4;
#pragma unroll
  for (int j = 0; j < 4; j++) {
    int col = n0 + wn + j * 16 + fr;
    float bj = bias[col];
#pragma unroll
    for (int i = 0; i < 4; i++) {
#pragma unroll
      for (int r = 0; r < 4; r++) {
        int row = m0 + wm + i * 16 + q * 4 + r;
        if (row < M) {
          float v = acc[i][j][r] + bj;
          if (RELU) v = fmaxf(v, 0.f);
          C[(size_t)row * N + col] = f2bf(v);
        }
      }
    }
  }
}

// ---------------- readout: out[g] = b + sum_{i in g} dot(H[i,:512], w) -------
__global__ __launch_bounds__(256)
void init_out_kernel(float* __restrict__ out, const float* __restrict__ b_task) {
  int g = blockIdx.x * 256 + threadIdx.x;
  if (g < N_GRAPHS) out[g] = b_task[0];
}

__global__ __launch_bounds__(256)
void dot_pool_kernel(const unsigned short* __restrict__ H, const float* __restrict__ w,
                     const int* __restrict__ batch, float* __restrict__ out) {
  const int node = blockIdx.x * 4 + (threadIdx.x >> 6);
  const int lane = threadIdx.x & 63;
  uint4 hv = *(const uint4*)(H + (size_t)node * 512 + lane * 8);
  float4 w0 = *(const float4*)(w + lane * 8);
  float4 w1 = *(const float4*)(w + lane * 8 + 4);
  unsigned int p[4] = {hv.x, hv.y, hv.z, hv.w};
  float v = 0.f;
  v = fmaf(bf2f((unsigned short)(p[0] & 0xFFFF)), w0.x, v);
  v = fmaf(bf2f((unsigned short)(p[0] >> 16)),    w0.y, v);
  v = fmaf(bf2f((unsigned short)(p[1] & 0xFFFF)), w0.z, v);
  v = fmaf(bf2f((unsigned short)(p[1] >> 16)),    w0.w, v);
  v = fmaf(bf2f((unsigned short)(p[2] & 0xFFFF)), w1.x, v);
  v = fmaf(bf2f((unsigned short)(p[2] >> 16)),    w1.y, v);
  v = fmaf(bf2f((unsigned short)(p[3] & 0xFFFF)), w1.z, v);
  v = fmaf(bf2f((unsigned short)(p[3] >> 16)),    w1.w, v);
#pragma unroll
  for (int off = 32; off > 0; off >>= 1) v += __shfl_down(v, off);
  if (lane == 0) unsafeAtomicAdd(&out[batch[node]], v);
}

extern "C" void kernel_launch(void* const* d_in, const int* in_sizes, int n_in,
                              void* d_out, int out_size, void* d_ws, size_t ws_size,
                              hipStream_t stream) {
  const float* x       = (const float*)d_in[0];
  const int*   ei      = (const int*)d_in[1];
  const int*   batch   = (const int*)d_in[2];
  const float* W_embed = (const float*)d_in[3];
  const float* b_embed = (const float*)d_in[4];
  const float* eps     = (const float*)d_in[5];
  const float* W1[3] = {(const float*)d_in[6],  (const float*)d_in[10], (const float*)d_in[14]};
  const float* B1[3] = {(const float*)d_in[7],  (const float*)d_in[11], (const float*)d_in[15]};
  const float* W2[3] = {(const float*)d_in[8],  (const float*)d_in[12], (const float*)d_in[16]};
  const float* B2[3] = {(const float*)d_in[9],  (const float*)d_in[13], (const float*)d_in[17]};
  const float* W_task = (const float*)d_in[18];
  const float* b_task = (const float*)d_in[19];
  float* out = (float*)d_out;

  // layout (206.9 MB):
  //   RH @ 0        51.2 MB  bf16 H0/H1/H2 (<=256 wide); T2 spans RH+RB at l=2
  //   RB @ 51.2e6   51.2 MB  bf16 T0/T1 (256 wide)
  //   RZ @ 102.4e6 102.4 MB  fp32 Z (<=256 wide); H3 (512 bf16) written here
  //   CSR @ 204.8e6  ~2 MB   row_ptr / cursor / csr_src / blk_sums / blk_off
  const size_t OFF_RB  = 51200000;
  const size_t OFF_RZ  = 102400000;
  const size_t OFF_CSR = 204800000;
  if (ws_size < OFF_CSR + 2100000) return;
  unsigned short* RH = (unsigned short*)d_ws;
  unsigned short* RB = (unsigned short*)((char*)d_ws + OFF_RB);
  float*          RZ = (float*)((char*)d_ws + OFF_RZ);
  unsigned short* T2 = RH;                      // spans RH+RB (l=2 only)
  unsigned short* H3 = (unsigned short*)RZ;     // overwrites Z2 after it's dead
  char* csr_base = (char*)d_ws + OFF_CSR;
  int* row_ptr  = (int*)(csr_base);             // 100001 ints
  int* cursor   = (int*)(csr_base + 400016);    // 100000 ints (also deg histogram)
  int* csr_src  = (int*)(csr_base + 800016);    // 300000 ints
  int* blk_sums = (int*)(csr_base + 2000016);   // 98 ints
  int* blk_off  = (int*)(csr_base + 2000416);   // 98 ints

  // ---- CSR build (graph is layer-invariant; build once) ----
  zero_kernel<<<(N_NODES + 255) / 256, 256, 0, stream>>>(cursor, N_NODES);
  hist_kernel<<<(E_EDGES + 255) / 256, 256, 0, stream>>>(ei, cursor);
  scan_blk_kernel<<<98, 256, 0, stream>>>(cursor, row_ptr, blk_sums, N_NODES, N_NODES + 1);
  scan_blk_kernel<<<1, 256, 0, stream>>>(blk_sums, blk_off, nullptr, 98, 98);
  scan_fix_kernel<<<(N_NODES + 256) / 256, 256, 0, stream>>>(row_ptr, blk_off, cursor);
  fill_kernel<<<(E_EDGES + 255) / 256, 256, 0, stream>>>(ei, cursor, csr_src);

  // ---- embed -> H0 (128 wide) ----
  embed_kernel<<<N_NODES / 16, 128, 0, stream>>>(x, W_embed, b_embed, RH);

  const int Din[3]  = {128, 256, 256};
  const int Dhid[3] = {256, 256, 512};
  const int Dout[3] = {256, 256, 512};

  for (int l = 0; l < 3; l++) {
    const int di = Din[l];
    dim3 g1((N_NODES + 127) / 128, Dhid[l] / 128);
    dim3 g2((N_NODES + 127) / 128, Dout[l] / 128);
    unsigned short* Tdst = (l == 2) ? T2 : RB;
    unsigned short* Hdst = (l == 2) ? H3 : RH;

    // Z = (1+eps)*H[dst] + sum H[src]  (fp32, CSR gather, no atomics)
    if (di == 128)
      gather_kernel<2><<<N_NODES / 4, 256, 0, stream>>>(RH, RZ, row_ptr, csr_src, eps, l);
    else
      gather_kernel<4><<<N_NODES / 4, 256, 0, stream>>>(RH, RZ, row_ptr, csr_src, eps, l);
    // T = relu(Z @ W1 + b1)
    gemm_kernel<false, true><<<g1, 256, 0, stream>>>(RZ, W1[l], B1[l], Tdst, N_NODES, di, Dhid[l]);
    // H = act(T @ W2 + b2); relu only for l < 2
    if (l < 2)
      gemm_kernel<true, true><<<g2, 256, 0, stream>>>(Tdst, W2[l], B2[l], Hdst, N_NODES, Dhid[l], Dout[l]);
    else
      gemm_kernel<true, false><<<g2, 256, 0, stream>>>(Tdst, W2[l], B2[l], Hdst, N_NODES, Dhid[l], Dout[l]);
  }

  // ---- readout: out[g] = b + sum dot(h_i, w) ----
  init_out_kernel<<<(N_GRAPHS + 255) / 256, 256, 0, stream>>>(out, b_task);
  dot_pool_kernel<<<N_NODES / 4, 256, 0, stream>>>(H3, W_task, batch, out);
}

// Round 4
// 728.633 us; speedup vs baseline: 4.5625x; 1.2923x over previous
//
#include <hip/hip_runtime.h>

#define N_NODES 100000
#define E_EDGES 300000
#define N_GRAPHS 2048

typedef float  floatx4 __attribute__((ext_vector_type(4)));
typedef short  shortx8 __attribute__((ext_vector_type(8)));

__device__ __forceinline__ float bf2f(unsigned short u) {
  return __uint_as_float(((unsigned int)u) << 16);
}
__device__ __forceinline__ unsigned short f2bf(float f) {
  unsigned int u = __float_as_uint(f);
  u += 0x7FFFu + ((u >> 16) & 1u);
  return (unsigned short)(u >> 16);
}

// async global->LDS, 16B per lane; lds base must be wave-uniform
__device__ __forceinline__ void cp16(const void* g, void* l) {
  __builtin_amdgcn_global_load_lds(
      (const __attribute__((address_space(1))) unsigned int*)g,
      (__attribute__((address_space(3))) unsigned int*)l, 16, 0, 0);
}

// ---------------- embed: H[n,128] = bf16(X[n,40] @ We[40,128] + be) ----------
__global__ __launch_bounds__(128)
void embed_kernel(const float* __restrict__ X, const float* __restrict__ W,
                  const float* __restrict__ b, unsigned short* __restrict__ H) {
  __shared__ float Ws[40 * 128];
  __shared__ float Xs[16 * 40];
  const int t = threadIdx.x;
  const int nb = blockIdx.x * 16;
  for (int i = t; i < 40 * 128; i += 128) Ws[i] = W[i];
  for (int i = t; i < 16 * 40; i += 128) Xs[i] = X[(size_t)nb * 40 + i];
  __syncthreads();
  const float bias = b[t];
  for (int n = 0; n < 16; n++) {
    float acc = bias;
#pragma unroll
    for (int k = 0; k < 40; k++) acc = fmaf(Xs[n * 40 + k], Ws[k * 128 + t], acc);
    H[(size_t)(nb + n) * 128 + t] = f2bf(acc);
  }
}

// ---------------- W[k,n] fp32 -> Wt[n,k] bf16 (32x32 LDS tile) ---------------
__global__ __launch_bounds__(256)
void wt_kernel(const float* __restrict__ W, unsigned short* __restrict__ Wt,
               int K, int N) {
  __shared__ unsigned short tile[32][33];
  const int kb = blockIdx.x * 32, nb = blockIdx.y * 32;
  const int tx = threadIdx.x & 31, ty = threadIdx.x >> 5;
  for (int r = ty; r < 32; r += 8)
    tile[r][tx] = f2bf(W[(size_t)(kb + r) * N + nb + tx]);
  __syncthreads();
  for (int r = ty; r < 32; r += 8)
    Wt[(size_t)(nb + r) * K + kb + tx] = tile[tx][r];
}

// ---------------- CSR build: zero, histogram, scan, fill ---------------------
__global__ __launch_bounds__(256)
void zero_kernel(int* __restrict__ p, int n) {
  int i = blockIdx.x * 256 + threadIdx.x;
  if (i < n) p[i] = 0;
}

__global__ __launch_bounds__(256)
void hist_kernel(const int* __restrict__ ei, int* __restrict__ deg) {
  int e = blockIdx.x * 256 + threadIdx.x;
  if (e < E_EDGES) atomicAdd(&deg[ei[E_EDGES + e]], 1);
}

__global__ __launch_bounds__(256)
void scan_blk_kernel(const int* __restrict__ in, int* __restrict__ out,
                     int* __restrict__ blk_sums, int n_in, int n_out) {
  __shared__ int sm[256];
  const int t = threadIdx.x;
  const int base = blockIdx.x * 1024 + t * 4;
  int d0 = (base + 0 < n_in) ? in[base + 0] : 0;
  int d1 = (base + 1 < n_in) ? in[base + 1] : 0;
  int d2 = (base + 2 < n_in) ? in[base + 2] : 0;
  int d3 = (base + 3 < n_in) ? in[base + 3] : 0;
  int s = d0 + d1 + d2 + d3;
  sm[t] = s;
  __syncthreads();
  for (int off = 1; off < 256; off <<= 1) {
    int v = (t >= off) ? sm[t - off] : 0;
    __syncthreads();
    sm[t] += v;
    __syncthreads();
  }
  int excl = sm[t] - s;
  if (base + 0 < n_out) out[base + 0] = excl;
  if (base + 1 < n_out) out[base + 1] = excl + d0;
  if (base + 2 < n_out) out[base + 2] = excl + d0 + d1;
  if (base + 3 < n_out) out[base + 3] = excl + d0 + d1 + d2;
  if (t == 255 && blk_sums) blk_sums[blockIdx.x] = sm[255];
}

__global__ __launch_bounds__(256)
void scan_fix_kernel(int* __restrict__ row_ptr, const int* __restrict__ blk_off,
                     int* __restrict__ cursor) {
  int i = blockIdx.x * 256 + threadIdx.x;
  if (i <= N_NODES) {
    int v = row_ptr[i] + blk_off[i >> 10];
    row_ptr[i] = v;
    if (i < N_NODES) cursor[i] = v;
  }
}

__global__ __launch_bounds__(256)
void fill_kernel(const int* __restrict__ ei, int* __restrict__ cursor,
                 int* __restrict__ csr_src) {
  int e = blockIdx.x * 256 + threadIdx.x;
  if (e < E_EDGES) {
    int d = ei[E_EDGES + e];
    int slot = atomicAdd(&cursor[d], 1);
    csr_src[slot] = ei[e];
  }
}

// ------- gather: Z[d] = bf16((1+eps)*H[d] + sum_{s->d} H[s]), fp32 accum -----
template <int NV>  // NV bf16 feats per lane, D = NV*64
__global__ __launch_bounds__(256)
void gather_kernel(const unsigned short* __restrict__ H, unsigned short* __restrict__ Z,
                   const int* __restrict__ row_ptr, const int* __restrict__ csr,
                   const float* __restrict__ eps, int l) {
  const int D = NV * 64;
  const int node = blockIdx.x * 4 + (threadIdx.x >> 6);
  const int lane = threadIdx.x & 63;
  const float sc = 1.0f + eps[l];
  const unsigned short* hp0 = H + (size_t)node * D + lane * NV;
  float acc[NV];
  if constexpr (NV == 4) {
    uint2 hv = *(const uint2*)hp0;
    acc[0] = sc * bf2f((unsigned short)(hv.x & 0xFFFF));
    acc[1] = sc * bf2f((unsigned short)(hv.x >> 16));
    acc[2] = sc * bf2f((unsigned short)(hv.y & 0xFFFF));
    acc[3] = sc * bf2f((unsigned short)(hv.y >> 16));
  } else {
    unsigned int hv = *(const unsigned int*)hp0;
    acc[0] = sc * bf2f((unsigned short)(hv & 0xFFFF));
    acc[1] = sc * bf2f((unsigned short)(hv >> 16));
  }
  const int e0 = row_ptr[node];
  const int e1 = row_ptr[node + 1];
  int e = e0;
  for (; e + 2 <= e1; e += 2) {
    int s0 = csr[e], s1 = csr[e + 1];
    const unsigned short* p0 = H + (size_t)s0 * D + lane * NV;
    const unsigned short* p1 = H + (size_t)s1 * D + lane * NV;
    if constexpr (NV == 4) {
      uint2 a = *(const uint2*)p0;
      uint2 b = *(const uint2*)p1;
      acc[0] += bf2f((unsigned short)(a.x & 0xFFFF)) + bf2f((unsigned short)(b.x & 0xFFFF));
      acc[1] += bf2f((unsigned short)(a.x >> 16))    + bf2f((unsigned short)(b.x >> 16));
      acc[2] += bf2f((unsigned short)(a.y & 0xFFFF)) + bf2f((unsigned short)(b.y & 0xFFFF));
      acc[3] += bf2f((unsigned short)(a.y >> 16))    + bf2f((unsigned short)(b.y >> 16));
    } else {
      unsigned int a = *(const unsigned int*)p0;
      unsigned int b = *(const unsigned int*)p1;
      acc[0] += bf2f((unsigned short)(a & 0xFFFF)) + bf2f((unsigned short)(b & 0xFFFF));
      acc[1] += bf2f((unsigned short)(a >> 16))    + bf2f((unsigned short)(b >> 16));
    }
  }
  if (e < e1) {
    int s0 = csr[e];
    const unsigned short* p0 = H + (size_t)s0 * D + lane * NV;
    if constexpr (NV == 4) {
      uint2 a = *(const uint2*)p0;
      acc[0] += bf2f((unsigned short)(a.x & 0xFFFF));
      acc[1] += bf2f((unsigned short)(a.x >> 16));
      acc[2] += bf2f((unsigned short)(a.y & 0xFFFF));
      acc[3] += bf2f((unsigned short)(a.y >> 16));
    } else {
      unsigned int a = *(const unsigned int*)p0;
      acc[0] += bf2f((unsigned short)(a & 0xFFFF));
      acc[1] += bf2f((unsigned short)(a >> 16));
    }
  }
  unsigned short* zp = Z + (size_t)node * D + lane * NV;
  if constexpr (NV == 4) {
    unsigned short z[4] = {f2bf(acc[0]), f2bf(acc[1]), f2bf(acc[2]), f2bf(acc[3])};
    *(uint2*)zp = *(uint2*)z;
  } else {
    unsigned short z[2] = {f2bf(acc[0]), f2bf(acc[1])};
    *(unsigned int*)zp = *(unsigned int*)z;
  }
}

// ---------------- GEMM: C = act(A[M,K] @ Bt[N,K]^T + bias), m97-style --------
// MODE 0: C bf16 store with relu. MODE 1: plain store. MODE 2: fused task-dot:
//   nodedot[row] += sum_col (acc+bias[col]) * wtask[col]   (no C store)
template <int MODE>
__global__ __launch_bounds__(256)
void gemm_bt_kernel(const unsigned short* __restrict__ A, const unsigned short* __restrict__ Bt,
                    const float* __restrict__ bias, unsigned short* __restrict__ C,
                    const float* __restrict__ wtask, float* __restrict__ nodedot,
                    int M, int K, int N) {
  constexpr int BM = 128, BN = 128, BK = 32;
  __shared__ unsigned short As[BM * BK];  // k-major, unpadded (global_load_lds layout)
  __shared__ unsigned short Bs[BN * BK];
  const int tid = threadIdx.x;
  const int lane = tid & 63;
  const int wave = tid >> 6;
  const int m0 = blockIdx.x * BM;
  const int n0 = blockIdx.y * BN;
  const int wm = (wave & 1) * 64;
  const int wn = (wave >> 1) * 64;

  floatx4 acc[4][4];
#pragma unroll
  for (int i = 0; i < 4; i++)
#pragma unroll
    for (int j = 0; j < 4; j++) acc[i][j] = (floatx4){0.f, 0.f, 0.f, 0.f};

  // staging: chunk c (16B) holds row c>>2, k-bytes [(c&3)*16 ..). Wave handles
  // chunks [wave*128, wave*128+128): two 64-chunk calls, lds base wave-uniform.
  const int c0 = wave * 128 + lane;
  const int c1 = c0 + 64;
  const int rA0 = c0 >> 2, kO0 = (c0 & 3) * 8;
  const int rA1 = c1 >> 2, kO1 = (c1 & 3) * 8;
  const unsigned short* gA0 = A + (size_t)(m0 + rA0) * K + kO0;
  const unsigned short* gA1 = A + (size_t)(m0 + rA1) * K + kO1;
  const unsigned short* gB0 = Bt + (size_t)(n0 + rA0) * K + kO0;
  const unsigned short* gB1 = Bt + (size_t)(n0 + rA1) * K + kO1;
  unsigned short* lA0 = &As[wave * 1024];
  unsigned short* lA1 = &As[wave * 1024 + 512];
  unsigned short* lB0 = &Bs[wave * 1024];
  unsigned short* lB1 = &Bs[wave * 1024 + 512];

  const int fr = lane & 15;
  const int fq = lane >> 4;

  for (int k0 = 0; k0 < K; k0 += BK) {
    cp16(gA0 + k0, lA0);
    cp16(gA1 + k0, lA1);
    cp16(gB0 + k0, lB0);
    cp16(gB1 + k0, lB1);
    __syncthreads();
    shortx8 af[4], bf[4];
#pragma unroll
    for (int i = 0; i < 4; i++)
      af[i] = *(const shortx8*)&As[(wm + i * 16 + fr) * BK + fq * 8];
#pragma unroll
    for (int j = 0; j < 4; j++)
      bf[j] = *(const shortx8*)&Bs[(wn + j * 16 + fr) * BK + fq * 8];
#pragma unroll
    for (int i = 0; i < 4; i++)
#pragma unroll
      for (int j = 0; j < 4; j++)
        acc[i][j] = __builtin_amdgcn_mfma_f32_16x16x32_bf16(af[i], bf[j], acc[i][j], 0, 0, 0);
    __syncthreads();
  }

  // epilogue: C/D layout col=lane&15, row=(lane>>4)*4+r
  if (MODE == 2) {
    float wv[4], bj[4];
#pragma unroll
    for (int j = 0; j < 4; j++) {
      int col = n0 + wn + j * 16 + fr;
      wv[j] = wtask[col];
      bj[j] = bias[col];
    }
#pragma unroll
    for (int i = 0; i < 4; i++) {
#pragma unroll
      for (int r = 0; r < 4; r++) {
        float p = 0.f;
#pragma unroll
        for (int j = 0; j < 4; j++) p += (acc[i][j][r] + bj[j]) * wv[j];
#pragma unroll
        for (int off = 1; off < 16; off <<= 1) p += __shfl_xor(p, off);
        if (fr == 0) {
          int row = m0 + wm + i * 16 + fq * 4 + r;
          if (row < M) unsafeAtomicAdd(&nodedot[row], p);
        }
      }
    }
  } else {
#pragma unroll
    for (int j = 0; j < 4; j++) {
      int col = n0 + wn + j * 16 + fr;
      float bj = bias[col];
#pragma unroll
      for (int i = 0; i < 4; i++) {
#pragma unroll
        for (int r = 0; r < 4; r++) {
          int row = m0 + wm + i * 16 + fq * 4 + r;
          if (row < M) {
            float v = acc[i][j][r] + bj;
            if (MODE == 0) v = fmaxf(v, 0.f);
            C[(size_t)row * N + col] = f2bf(v);
          }
        }
      }
    }
  }
}

// ---------------- readout ----------------------------------------------------
__global__ __launch_bounds__(256)
void init_out_kernel(float* __restrict__ out, const float* __restrict__ b_task) {
  int g = blockIdx.x * 256 + threadIdx.x;
  if (g < N_GRAPHS) out[g] = b_task[0];
}

// segmented sum of nodedot over sorted batch; 64 nodes per thread
__global__ __launch_bounds__(256)
void pool_kernel(const float* __restrict__ nodedot, const int* __restrict__ batch,
                 float* __restrict__ out) {
  int t = blockIdx.x * 256 + threadIdx.x;
  int i0 = t * 64;
  if (i0 >= N_NODES) return;
  int i1 = i0 + 64;
  if (i1 > N_NODES) i1 = N_NODES;
  int g = batch[i0];
  float s = 0.f;
  for (int i = i0; i < i1; i++) {
    int gi = batch[i];
    if (gi != g) { unsafeAtomicAdd(&out[g], s); g = gi; s = 0.f; }
    s += nodedot[i];
  }
  unsafeAtomicAdd(&out[g], s);
}

extern "C" void kernel_launch(void* const* d_in, const int* in_sizes, int n_in,
                              void* d_out, int out_size, void* d_ws, size_t ws_size,
                              hipStream_t stream) {
  const float* x       = (const float*)d_in[0];
  const int*   ei      = (const int*)d_in[1];
  const int*   batch   = (const int*)d_in[2];
  const float* W_embed = (const float*)d_in[3];
  const float* b_embed = (const float*)d_in[4];
  const float* eps     = (const float*)d_in[5];
  const float* W1[3] = {(const float*)d_in[6],  (const float*)d_in[10], (const float*)d_in[14]};
  const float* B1[3] = {(const float*)d_in[7],  (const float*)d_in[11], (const float*)d_in[15]};
  const float* W2[3] = {(const float*)d_in[8],  (const float*)d_in[12], (const float*)d_in[16]};
  const float* B2[3] = {(const float*)d_in[9],  (const float*)d_in[13], (const float*)d_in[17]};
  const float* W_task = (const float*)d_in[18];
  const float* b_task = (const float*)d_in[19];
  float* out = (float*)d_out;

  // layout (~158 MB):
  //   RH @ 0         51.2 MB bf16 H (<=256 wide); T2 [100k,512] spans RH+RB
  //   RB @ 51.2e6    51.2 MB bf16 T0/T1
  //   RZ @ 102.4e6   51.2 MB bf16 Z
  //   AUX @ 153.6e6  CSR + nodedot + Wt (bf16 transposed weights)
  const size_t OFF_RB  = 51200000;
  const size_t OFF_RZ  = 102400000;
  const size_t OFF_AUX = 153600000;
  if (ws_size < OFF_AUX + 4000000) return;
  unsigned short* RH = (unsigned short*)d_ws;
  unsigned short* RB = (unsigned short*)((char*)d_ws + OFF_RB);
  unsigned short* RZ = (unsigned short*)((char*)d_ws + OFF_RZ);
  unsigned short* T2 = RH;  // 100k x 512, spans RH+RB (l=2 only; H2/T1 dead)
  char* aux = (char*)d_ws + OFF_AUX;
  int* row_ptr  = (int*)(aux);               // 100001 ints
  int* cursor   = (int*)(aux + 400016);      // 100000 ints (also deg histogram)
  int* csr_src  = (int*)(aux + 800016);      // 300000 ints
  int* blk_sums = (int*)(aux + 2000016);     // 98 ints
  int* blk_off  = (int*)(aux + 2000416);     // 98 ints
  float* nodedot = (float*)(aux + 2000816);  // 100000 floats
  unsigned short* WT = (unsigned short*)(aux + 2400832);  // 622592 bf16
  unsigned short* Wt1[3] = {WT,          WT + 98304,  WT + 229376};
  unsigned short* Wt2[3] = {WT + 32768,  WT + 163840, WT + 360448};

  // ---- weight transpose+convert: Wt[n,k] = bf16(W[k,n]) ----
  wt_kernel<<<dim3(128 / 32, 256 / 32), 256, 0, stream>>>(W1[0], Wt1[0], 128, 256);
  wt_kernel<<<dim3(256 / 32, 256 / 32), 256, 0, stream>>>(W2[0], Wt2[0], 256, 256);
  wt_kernel<<<dim3(256 / 32, 256 / 32), 256, 0, stream>>>(W1[1], Wt1[1], 256, 256);
  wt_kernel<<<dim3(256 / 32, 256 / 32), 256, 0, stream>>>(W2[1], Wt2[1], 256, 256);
  wt_kernel<<<dim3(256 / 32, 512 / 32), 256, 0, stream>>>(W1[2], Wt1[2], 256, 512);
  wt_kernel<<<dim3(512 / 32, 512 / 32), 256, 0, stream>>>(W2[2], Wt2[2], 512, 512);

  // ---- CSR build ----
  zero_kernel<<<(N_NODES + 255) / 256, 256, 0, stream>>>(cursor, N_NODES);
  hist_kernel<<<(E_EDGES + 255) / 256, 256, 0, stream>>>(ei, cursor);
  scan_blk_kernel<<<98, 256, 0, stream>>>(cursor, row_ptr, blk_sums, N_NODES, N_NODES + 1);
  scan_blk_kernel<<<1, 256, 0, stream>>>(blk_sums, blk_off, nullptr, 98, 98);
  scan_fix_kernel<<<(N_NODES + 256) / 256, 256, 0, stream>>>(row_ptr, blk_off, cursor);
  fill_kernel<<<(E_EDGES + 255) / 256, 256, 0, stream>>>(ei, cursor, csr_src);

  // ---- nodedot = 0 ----
  zero_kernel<<<(N_NODES + 255) / 256, 256, 0, stream>>>((int*)nodedot, N_NODES);

  // ---- embed -> H0 (128 wide) ----
  embed_kernel<<<N_NODES / 16, 128, 0, stream>>>(x, W_embed, b_embed, RH);

  const int Din[3]  = {128, 256, 256};
  const int Dhid[3] = {256, 256, 512};
  const int Dout[3] = {256, 256, 512};
  const int MB = (N_NODES + 127) / 128;

  for (int l = 0; l < 3; l++) {
    const int di = Din[l];
    unsigned short* Tdst = (l == 2) ? T2 : RB;
    // Z = bf16((1+eps)*H[dst] + sum H[src])
    if (di == 128)
      gather_kernel<2><<<N_NODES / 4, 256, 0, stream>>>(RH, RZ, row_ptr, csr_src, eps, l);
    else
      gather_kernel<4><<<N_NODES / 4, 256, 0, stream>>>(RH, RZ, row_ptr, csr_src, eps, l);
    // T = relu(Z @ W1 + b1)
    gemm_bt_kernel<0><<<dim3(MB, Dhid[l] / 128), 256, 0, stream>>>(
        RZ, Wt1[l], B1[l], Tdst, nullptr, nullptr, N_NODES, di, Dhid[l]);
    // H = act(T @ W2 + b2): l<2 relu-store; l==2 fused task-dot (plain)
    if (l < 2)
      gemm_bt_kernel<0><<<dim3(MB, Dout[l] / 128), 256, 0, stream>>>(
          Tdst, Wt2[l], B2[l], RH, nullptr, nullptr, N_NODES, Dhid[l], Dout[l]);
    else
      gemm_bt_kernel<2><<<dim3(MB, Dout[l] / 128), 256, 0, stream>>>(
          Tdst, Wt2[l], B2[l], nullptr, W_task, nodedot, N_NODES, Dhid[l], Dout[l]);
  }

  // ---- out[g] = b + segmented sum of nodedot ----
  init_out_kernel<<<(N_GRAPHS + 255) / 256, 256, 0, stream>>>(out, b_task);
  pool_kernel<<<((N_NODES + 63) / 64 + 255) / 256, 256, 0, stream>>>(nodedot, batch, out);
}

// Round 5
// 615.104 us; speedup vs baseline: 5.4046x; 1.1846x over previous
//
#include <hip/hip_runtime.h>

#define N_NODES 100000
#define E_EDGES 300000
#define N_GRAPHS 2048

typedef float  floatx4 __attribute__((ext_vector_type(4)));
typedef short  shortx8 __attribute__((ext_vector_type(8)));

__device__ __forceinline__ float bf2f(unsigned short u) {
  return __uint_as_float(((unsigned int)u) << 16);
}
__device__ __forceinline__ unsigned short f2bf(float f) {
  unsigned int u = __float_as_uint(f);
  u += 0x7FFFu + ((u >> 16) & 1u);
  return (unsigned short)(u >> 16);
}

// async global->LDS, 16B per lane; lds base must be wave-uniform
__device__ __forceinline__ void cp16(const void* g, void* l) {
  __builtin_amdgcn_global_load_lds(
      (const __attribute__((address_space(1))) unsigned int*)g,
      (__attribute__((address_space(3))) unsigned int*)l, 16, 0, 0);
}

// ---------------- embed: H[n,128] = bf16(X[n,40] @ We[40,128] + be) ----------
__global__ __launch_bounds__(128)
void embed_kernel(const float* __restrict__ X, const float* __restrict__ W,
                  const float* __restrict__ b, unsigned short* __restrict__ H) {
  __shared__ float Ws[40 * 128];
  __shared__ float Xs[16 * 40];
  const int t = threadIdx.x;
  const int nb = blockIdx.x * 16;
  for (int i = t; i < 40 * 128; i += 128) Ws[i] = W[i];
  for (int i = t; i < 16 * 40; i += 128) Xs[i] = X[(size_t)nb * 40 + i];
  __syncthreads();
  const float bias = b[t];
  for (int n = 0; n < 16; n++) {
    float acc = bias;
#pragma unroll
    for (int k = 0; k < 40; k++) acc = fmaf(Xs[n * 40 + k], Ws[k * 128 + t], acc);
    H[(size_t)(nb + n) * 128 + t] = f2bf(acc);
  }
}

// -------- batched W[k,n] fp32 -> Wt[n,k] bf16 (32x32 LDS tiles, 5 jobs) ------
struct WtJobs {
  const float* W[5];
  unsigned short* Wt[5];
  int K[5];
  int N[5];
};

__global__ __launch_bounds__(256)
void wt5_kernel(WtJobs j) {
  __shared__ unsigned short tile[32][33];
  const int z = blockIdx.z;
  const int K = j.K[z], N = j.N[z];
  const int kb = blockIdx.x * 32, nb = blockIdx.y * 32;
  if (kb >= K || nb >= N) return;
  const float* W = j.W[z];
  unsigned short* Wt = j.Wt[z];
  const int tx = threadIdx.x & 31, ty = threadIdx.x >> 5;
  for (int r = ty; r < 32; r += 8)
    tile[r][tx] = f2bf(W[(size_t)(kb + r) * N + nb + tx]);
  __syncthreads();
  for (int r = ty; r < 32; r += 8)
    Wt[(size_t)(nb + r) * K + kb + tx] = tile[tx][r];
}

// ---- w2v[k] = sum_n W2_2[k,n]*wtask[n]; c2 = sum_n b2[n]*wtask[n] -----------
__global__ __launch_bounds__(256)
void w2v_kernel(const float* __restrict__ W2, const float* __restrict__ b2,
                const float* __restrict__ wt, float* __restrict__ w2v,
                float* __restrict__ c2) {
  int k = blockIdx.x * 256 + threadIdx.x;
  if (k < 512) {
    float s = 0.f;
    for (int n = 0; n < 512; n++) s = fmaf(W2[(size_t)k * 512 + n], wt[n], s);
    w2v[k] = s;
  }
  if (blockIdx.x == 0 && threadIdx.x == 0) {
    float s = 0.f;
    for (int n = 0; n < 512; n++) s = fmaf(b2[n], wt[n], s);
    *c2 = s;
  }
}

__global__ __launch_bounds__(256)
void init_nd_kernel(float* __restrict__ nd, const float* __restrict__ c2) {
  int i = blockIdx.x * 256 + threadIdx.x;
  if (i < N_NODES) nd[i] = *c2;
}

// ---------------- CSR build: zero, histogram, scan, fill ---------------------
__global__ __launch_bounds__(256)
void zero_kernel(int* __restrict__ p, int n) {
  int i = blockIdx.x * 256 + threadIdx.x;
  if (i < n) p[i] = 0;
}

__global__ __launch_bounds__(256)
void hist_kernel(const int* __restrict__ ei, int* __restrict__ deg) {
  int e = blockIdx.x * 256 + threadIdx.x;
  if (e < E_EDGES) atomicAdd(&deg[ei[E_EDGES + e]], 1);
}

__global__ __launch_bounds__(256)
void scan_blk_kernel(const int* __restrict__ in, int* __restrict__ out,
                     int* __restrict__ blk_sums, int n_in, int n_out) {
  __shared__ int sm[256];
  const int t = threadIdx.x;
  const int base = blockIdx.x * 1024 + t * 4;
  int d0 = (base + 0 < n_in) ? in[base + 0] : 0;
  int d1 = (base + 1 < n_in) ? in[base + 1] : 0;
  int d2 = (base + 2 < n_in) ? in[base + 2] : 0;
  int d3 = (base + 3 < n_in) ? in[base + 3] : 0;
  int s = d0 + d1 + d2 + d3;
  sm[t] = s;
  __syncthreads();
  for (int off = 1; off < 256; off <<= 1) {
    int v = (t >= off) ? sm[t - off] : 0;
    __syncthreads();
    sm[t] += v;
    __syncthreads();
  }
  int excl = sm[t] - s;
  if (base + 0 < n_out) out[base + 0] = excl;
  if (base + 1 < n_out) out[base + 1] = excl + d0;
  if (base + 2 < n_out) out[base + 2] = excl + d0 + d1;
  if (base + 3 < n_out) out[base + 3] = excl + d0 + d1 + d2;
  if (t == 255 && blk_sums) blk_sums[blockIdx.x] = sm[255];
}

__global__ __launch_bounds__(256)
void scan_fix_kernel(int* __restrict__ row_ptr, const int* __restrict__ blk_off,
                     int* __restrict__ cursor) {
  int i = blockIdx.x * 256 + threadIdx.x;
  if (i <= N_NODES) {
    int v = row_ptr[i] + blk_off[i >> 10];
    row_ptr[i] = v;
    if (i < N_NODES) cursor[i] = v;
  }
}

__global__ __launch_bounds__(256)
void fill_kernel(const int* __restrict__ ei, int* __restrict__ cursor,
                 int* __restrict__ csr_src) {
  int e = blockIdx.x * 256 + threadIdx.x;
  if (e < E_EDGES) {
    int d = ei[E_EDGES + e];
    int slot = atomicAdd(&cursor[d], 1);
    csr_src[slot] = ei[e];
  }
}

// ------- gather: Z[d] = bf16((1+eps)*H[d] + sum_{s->d} H[s]), fp32 accum -----
template <int NV>  // NV bf16 feats per lane, D = NV*64
__global__ __launch_bounds__(256)
void gather_kernel(const unsigned short* __restrict__ H, unsigned short* __restrict__ Z,
                   const int* __restrict__ row_ptr, const int* __restrict__ csr,
                   const float* __restrict__ eps, int l) {
  const int D = NV * 64;
  const int node = blockIdx.x * 4 + (threadIdx.x >> 6);
  const int lane = threadIdx.x & 63;
  const float sc = 1.0f + eps[l];
  const unsigned short* hp0 = H + (size_t)node * D + lane * NV;
  float acc[NV];
  if constexpr (NV == 4) {
    uint2 hv = *(const uint2*)hp0;
    acc[0] = sc * bf2f((unsigned short)(hv.x & 0xFFFF));
    acc[1] = sc * bf2f((unsigned short)(hv.x >> 16));
    acc[2] = sc * bf2f((unsigned short)(hv.y & 0xFFFF));
    acc[3] = sc * bf2f((unsigned short)(hv.y >> 16));
  } else {
    unsigned int hv = *(const unsigned int*)hp0;
    acc[0] = sc * bf2f((unsigned short)(hv & 0xFFFF));
    acc[1] = sc * bf2f((unsigned short)(hv >> 16));
  }
  const int e0 = row_ptr[node];
  const int e1 = row_ptr[node + 1];
  int e = e0;
  for (; e + 2 <= e1; e += 2) {
    int s0 = csr[e], s1 = csr[e + 1];
    const unsigned short* p0 = H + (size_t)s0 * D + lane * NV;
    const unsigned short* p1 = H + (size_t)s1 * D + lane * NV;
    if constexpr (NV == 4) {
      uint2 a = *(const uint2*)p0;
      uint2 b = *(const uint2*)p1;
      acc[0] += bf2f((unsigned short)(a.x & 0xFFFF)) + bf2f((unsigned short)(b.x & 0xFFFF));
      acc[1] += bf2f((unsigned short)(a.x >> 16))    + bf2f((unsigned short)(b.x >> 16));
      acc[2] += bf2f((unsigned short)(a.y & 0xFFFF)) + bf2f((unsigned short)(b.y & 0xFFFF));
      acc[3] += bf2f((unsigned short)(a.y >> 16))    + bf2f((unsigned short)(b.y >> 16));
    } else {
      unsigned int a = *(const unsigned int*)p0;
      unsigned int b = *(const unsigned int*)p1;
      acc[0] += bf2f((unsigned short)(a & 0xFFFF)) + bf2f((unsigned short)(b & 0xFFFF));
      acc[1] += bf2f((unsigned short)(a >> 16))    + bf2f((unsigned short)(b >> 16));
    }
  }
  if (e < e1) {
    int s0 = csr[e];
    const unsigned short* p0 = H + (size_t)s0 * D + lane * NV;
    if constexpr (NV == 4) {
      uint2 a = *(const uint2*)p0;
      acc[0] += bf2f((unsigned short)(a.x & 0xFFFF));
      acc[1] += bf2f((unsigned short)(a.x >> 16));
      acc[2] += bf2f((unsigned short)(a.y & 0xFFFF));
      acc[3] += bf2f((unsigned short)(a.y >> 16));
    } else {
      unsigned int a = *(const unsigned int*)p0;
      acc[0] += bf2f((unsigned short)(a & 0xFFFF));
      acc[1] += bf2f((unsigned short)(a >> 16));
    }
  }
  unsigned short* zp = Z + (size_t)node * D + lane * NV;
  if constexpr (NV == 4) {
    unsigned short z[4] = {f2bf(acc[0]), f2bf(acc[1]), f2bf(acc[2]), f2bf(acc[3])};
    *(uint2*)zp = *(uint2*)z;
  } else {
    unsigned short z[2] = {f2bf(acc[0]), f2bf(acc[1])};
    *(unsigned int*)zp = *(unsigned int*)z;
  }
}

// ---------------- GEMM: act(A[M,K] @ Bt[N,K]^T + bias), m97-style ------------
// grid = (N/128, M/128): column-fastest so blocks sharing an A-tile are
// temporally adjacent (L2/LLC reuse of A across column blocks).
// MODE 0: C = bf16(relu(.)) store.
// MODE 3: fused relu+dot: nodedot[row] += sum_col relu(acc+bias)*w2v[col].
template <int MODE>
__global__ __launch_bounds__(256)
void gemm_bt_kernel(const unsigned short* __restrict__ A, const unsigned short* __restrict__ Bt,
                    const float* __restrict__ bias, unsigned short* __restrict__ C,
                    const float* __restrict__ w2v, float* __restrict__ nodedot,
                    int M, int K, int N) {
  constexpr int BM = 128, BN = 128, BK = 32;
  __shared__ unsigned short As[BM * BK];  // k-major, unpadded (global_load_lds layout)
  __shared__ unsigned short Bs[BN * BK];
  const int tid = threadIdx.x;
  const int lane = tid & 63;
  const int wave = tid >> 6;
  const int m0 = blockIdx.y * BM;
  const int n0 = blockIdx.x * BN;
  const int wm = (wave & 1) * 64;
  const int wn = (wave >> 1) * 64;

  floatx4 acc[4][4];
#pragma unroll
  for (int i = 0; i < 4; i++)
#pragma unroll
    for (int j = 0; j < 4; j++) acc[i][j] = (floatx4){0.f, 0.f, 0.f, 0.f};

  // staging: chunk c (16B) = row c>>2, k-bytes (c&3)*16. Wave covers chunks
  // [wave*128, wave*128+128): two 64-chunk cp16 calls, lds base wave-uniform.
  const int c0 = wave * 128 + lane;
  const int c1 = c0 + 64;
  const int rA0 = c0 >> 2, kO0 = (c0 & 3) * 8;
  const int rA1 = c1 >> 2, kO1 = (c1 & 3) * 8;
  const unsigned short* gA0 = A + (size_t)(m0 + rA0) * K + kO0;
  const unsigned short* gA1 = A + (size_t)(m0 + rA1) * K + kO1;
  const unsigned short* gB0 = Bt + (size_t)(n0 + rA0) * K + kO0;
  const unsigned short* gB1 = Bt + (size_t)(n0 + rA1) * K + kO1;
  unsigned short* lA0 = &As[wave * 1024];
  unsigned short* lA1 = &As[wave * 1024 + 512];
  unsigned short* lB0 = &Bs[wave * 1024];
  unsigned short* lB1 = &Bs[wave * 1024 + 512];

  const int fr = lane & 15;
  const int fq = lane >> 4;

  for (int k0 = 0; k0 < K; k0 += BK) {
    cp16(gA0 + k0, lA0);
    cp16(gA1 + k0, lA1);
    cp16(gB0 + k0, lB0);
    cp16(gB1 + k0, lB1);
    __syncthreads();
    shortx8 af[4], bf[4];
#pragma unroll
    for (int i = 0; i < 4; i++)
      af[i] = *(const shortx8*)&As[(wm + i * 16 + fr) * BK + fq * 8];
#pragma unroll
    for (int j = 0; j < 4; j++)
      bf[j] = *(const shortx8*)&Bs[(wn + j * 16 + fr) * BK + fq * 8];
#pragma unroll
    for (int i = 0; i < 4; i++)
#pragma unroll
      for (int j = 0; j < 4; j++)
        acc[i][j] = __builtin_amdgcn_mfma_f32_16x16x32_bf16(af[i], bf[j], acc[i][j], 0, 0, 0);
    __syncthreads();
  }

  // epilogue: C/D layout col=lane&15, row=(lane>>4)*4+r
  if (MODE == 3) {
    float wv[4], bj[4];
#pragma unroll
    for (int j = 0; j < 4; j++) {
      int col = n0 + wn + j * 16 + fr;
      wv[j] = w2v[col];
      bj[j] = bias[col];
    }
#pragma unroll
    for (int i = 0; i < 4; i++) {
#pragma unroll
      for (int r = 0; r < 4; r++) {
        float p = 0.f;
#pragma unroll
        for (int j = 0; j < 4; j++) p += fmaxf(acc[i][j][r] + bj[j], 0.f) * wv[j];
#pragma unroll
        for (int off = 1; off < 16; off <<= 1) p += __shfl_xor(p, off);
        if (fr == 0) {
          int row = m0 + wm + i * 16 + fq * 4 + r;
          if (row < M) unsafeAtomicAdd(&nodedot[row], p);
        }
      }
    }
  } else {
#pragma unroll
    for (int j = 0; j < 4; j++) {
      int col = n0 + wn + j * 16 + fr;
      float bj = bias[col];
#pragma unroll
      for (int i = 0; i < 4; i++) {
#pragma unroll
        for (int r = 0; r < 4; r++) {
          int row = m0 + wm + i * 16 + fq * 4 + r;
          if (row < M) {
            float v = fmaxf(acc[i][j][r] + bj, 0.f);
            C[(size_t)row * N + col] = f2bf(v);
          }
        }
      }
    }
  }
}

// ---------------- readout ----------------------------------------------------
__global__ __launch_bounds__(256)
void init_out_kernel(float* __restrict__ out, const float* __restrict__ b_task) {
  int g = blockIdx.x * 256 + threadIdx.x;
  if (g < N_GRAPHS) out[g] = b_task[0];
}

// segmented sum of nodedot over sorted batch; 64 nodes per thread
__global__ __launch_bounds__(256)
void pool_kernel(const float* __restrict__ nodedot, const int* __restrict__ batch,
                 float* __restrict__ out) {
  int t = blockIdx.x * 256 + threadIdx.x;
  int i0 = t * 64;
  if (i0 >= N_NODES) return;
  int i1 = i0 + 64;
  if (i1 > N_NODES) i1 = N_NODES;
  int g = batch[i0];
  float s = 0.f;
  for (int i = i0; i < i1; i++) {
    int gi = batch[i];
    if (gi != g) { unsafeAtomicAdd(&out[g], s); g = gi; s = 0.f; }
    s += nodedot[i];
  }
  unsafeAtomicAdd(&out[g], s);
}

extern "C" void kernel_launch(void* const* d_in, const int* in_sizes, int n_in,
                              void* d_out, int out_size, void* d_ws, size_t ws_size,
                              hipStream_t stream) {
  const float* x       = (const float*)d_in[0];
  const int*   ei      = (const int*)d_in[1];
  const int*   batch   = (const int*)d_in[2];
  const float* W_embed = (const float*)d_in[3];
  const float* b_embed = (const float*)d_in[4];
  const float* eps     = (const float*)d_in[5];
  const float* W1[3] = {(const float*)d_in[6],  (const float*)d_in[10], (const float*)d_in[14]};
  const float* B1[3] = {(const float*)d_in[7],  (const float*)d_in[11], (const float*)d_in[15]};
  const float* W2[3] = {(const float*)d_in[8],  (const float*)d_in[12], (const float*)d_in[16]};
  const float* B2[3] = {(const float*)d_in[9],  (const float*)d_in[13], (const float*)d_in[17]};
  const float* W_task = (const float*)d_in[18];
  const float* b_task = (const float*)d_in[19];
  float* out = (float*)d_out;

  // layout (~157 MB):
  //   RH @ 0         51.2 MB bf16 H (<=256 wide)
  //   RB @ 51.2e6    51.2 MB bf16 T0/T1 (256 wide)
  //   RZ @ 102.4e6   51.2 MB bf16 Z (<=256 wide)
  //   AUX @ 153.6e6  CSR + nodedot + Wt (bf16 transposed weights) + w2v + c2
  const size_t OFF_RB  = 51200000;
  const size_t OFF_RZ  = 102400000;
  const size_t OFF_AUX = 153600000;
  if (ws_size < OFF_AUX + 4000000) return;
  unsigned short* RH = (unsigned short*)d_ws;
  unsigned short* RB = (unsigned short*)((char*)d_ws + OFF_RB);
  unsigned short* RZ = (unsigned short*)((char*)d_ws + OFF_RZ);
  char* aux = (char*)d_ws + OFF_AUX;
  int* row_ptr  = (int*)(aux);               // 100001 ints
  int* cursor   = (int*)(aux + 400016);      // 100000 ints (also deg histogram)
  int* csr_src  = (int*)(aux + 800016);      // 300000 ints
  int* blk_sums = (int*)(aux + 2000016);     // 98 ints
  int* blk_off  = (int*)(aux + 2000416);     // 98 ints
  float* nodedot = (float*)(aux + 2000816);  // 100000 floats
  unsigned short* WT = (unsigned short*)(aux + 2400832);  // 360448 bf16
  float* w2v = (float*)(aux + 3200832);      // 512 floats
  float* c2  = (float*)(aux + 3202880);      // 1 float
  unsigned short* Wt1[3] = {WT,          WT + 98304,  WT + 229376};
  unsigned short* Wt2[2] = {WT + 32768,  WT + 163840};

  // ---- weight transpose+convert (5 jobs, one dispatch) ----
  WtJobs jobs;
  jobs.W[0] = W1[0]; jobs.Wt[0] = Wt1[0]; jobs.K[0] = 128; jobs.N[0] = 256;
  jobs.W[1] = W2[0]; jobs.Wt[1] = Wt2[0]; jobs.K[1] = 256; jobs.N[1] = 256;
  jobs.W[2] = W1[1]; jobs.Wt[2] = Wt1[1]; jobs.K[2] = 256; jobs.N[2] = 256;
  jobs.W[3] = W2[1]; jobs.Wt[3] = Wt2[1]; jobs.K[3] = 256; jobs.N[3] = 256;
  jobs.W[4] = W1[2]; jobs.Wt[4] = Wt1[2]; jobs.K[4] = 256; jobs.N[4] = 512;
  wt5_kernel<<<dim3(8, 16, 5), 256, 0, stream>>>(jobs);

  // ---- w2v = W2_2 @ w_task; c2 = b2_2 . w_task ----
  w2v_kernel<<<2, 256, 0, stream>>>(W2[2], B2[2], W_task, w2v, c2);

  // ---- CSR build ----
  zero_kernel<<<(N_NODES + 255) / 256, 256, 0, stream>>>(cursor, N_NODES);
  hist_kernel<<<(E_EDGES + 255) / 256, 256, 0, stream>>>(ei, cursor);
  scan_blk_kernel<<<98, 256, 0, stream>>>(cursor, row_ptr, blk_sums, N_NODES, N_NODES + 1);
  scan_blk_kernel<<<1, 256, 0, stream>>>(blk_sums, blk_off, nullptr, 98, 98);
  scan_fix_kernel<<<(N_NODES + 256) / 256, 256, 0, stream>>>(row_ptr, blk_off, cursor);
  fill_kernel<<<(E_EDGES + 255) / 256, 256, 0, stream>>>(ei, cursor, csr_src);

  // ---- nodedot[i] = c2 ----
  init_nd_kernel<<<(N_NODES + 255) / 256, 256, 0, stream>>>(nodedot, c2);

  // ---- embed -> H0 (128 wide) ----
  embed_kernel<<<N_NODES / 16, 128, 0, stream>>>(x, W_embed, b_embed, RH);

  const int MB = (N_NODES + 127) / 128;

  // ---- layer 0: 128 -> 256 -> 256 ----
  gather_kernel<2><<<N_NODES / 4, 256, 0, stream>>>(RH, RZ, row_ptr, csr_src, eps, 0);
  gemm_bt_kernel<0><<<dim3(2, MB), 256, 0, stream>>>(RZ, Wt1[0], B1[0], RB, nullptr, nullptr, N_NODES, 128, 256);
  gemm_bt_kernel<0><<<dim3(2, MB), 256, 0, stream>>>(RB, Wt2[0], B2[0], RH, nullptr, nullptr, N_NODES, 256, 256);

  // ---- layer 1: 256 -> 256 -> 256 ----
  gather_kernel<4><<<N_NODES / 4, 256, 0, stream>>>(RH, RZ, row_ptr, csr_src, eps, 1);
  gemm_bt_kernel<0><<<dim3(2, MB), 256, 0, stream>>>(RZ, Wt1[1], B1[1], RB, nullptr, nullptr, N_NODES, 256, 256);
  gemm_bt_kernel<0><<<dim3(2, MB), 256, 0, stream>>>(RB, Wt2[1], B2[1], RH, nullptr, nullptr, N_NODES, 256, 256);

  // ---- layer 2: 256 -> 512, second linear folded into w2v dot ----
  gather_kernel<4><<<N_NODES / 4, 256, 0, stream>>>(RH, RZ, row_ptr, csr_src, eps, 2);
  gemm_bt_kernel<3><<<dim3(4, MB), 256, 0, stream>>>(RZ, Wt1[2], B1[2], nullptr, w2v, nodedot, N_NODES, 256, 512);

  // ---- out[g] = b_task + segmented sum of nodedot ----
  init_out_kernel<<<(N_GRAPHS + 255) / 256, 256, 0, stream>>>(out, b_task);
  pool_kernel<<<((N_NODES + 63) / 64 + 255) / 256, 256, 0, stream>>>(nodedot, batch, out);
}